// Round 16
// baseline (107.451 us; speedup 1.0000x reference)
//
#include <hip/hip_runtime.h>
#include <hip/hip_bf16.h>

#define NN 2048
#define DD 128

typedef __attribute__((ext_vector_type(4))) float f32x4;
typedef __attribute__((ext_vector_type(8))) short short8;

__device__ __forceinline__ unsigned short f2bf_bits(float f) {
  union { __hip_bfloat16 h; unsigned short s; } u;
  u.h = __float2bfloat16(f);
  return u.s;
}

__device__ __forceinline__ short8 cvt8(f32x4 a, f32x4 b) {
  short8 r;
  r[0] = (short)f2bf_bits(a[0]); r[1] = (short)f2bf_bits(a[1]);
  r[2] = (short)f2bf_bits(a[2]); r[3] = (short)f2bf_bits(a[3]);
  r[4] = (short)f2bf_bits(b[0]); r[5] = (short)f2bf_bits(b[1]);
  r[6] = (short)f2bf_bits(b[2]); r[7] = (short)f2bf_bits(b[3]);
  return r;
}

__device__ __forceinline__ void gld16(const void* src, void* lds) {
  __builtin_amdgcn_global_load_lds(
      (const __attribute__((address_space(1))) void*)src,
      (__attribute__((address_space(3))) void*)lds, 16, 0, 0);
}

// ---------- K1: dnorm = rsqrt(rowsum(adj)+1e-8) (proven, ~21 µs) ----------
__global__ void k_degree(const float* __restrict__ adj, float* __restrict__ dnorm) {
  const int wv = threadIdx.x >> 6;
  const int ln = threadIdx.x & 63;
  const int row = blockIdx.x * 4 + wv;
  const f32x4* rowp = (const f32x4*)(adj + (size_t)row * NN);
  float s = 0.0f;
#pragma unroll
  for (int i = 0; i < 8; ++i) {
    f32x4 v = rowp[i * 64 + ln];
    s += v[0] + v[1] + v[2] + v[3];
  }
#pragma unroll
  for (int off = 32; off >= 1; off >>= 1) s += __shfl_xor(s, off);
  if (ln == 0) dnorm[row] = rsqrtf(s + 1e-8f);
}

// ---------- K2: yT[b][d][n] = bf16(dnorm[n] * (x@W)[n][d]) (proven) ----------
__global__ void k_y(const float* __restrict__ x, const float* __restrict__ W,
                    const float* __restrict__ dnorm, short* __restrict__ yT) {
  const int ln = threadIdx.x & 63;
  const int wv = threadIdx.x >> 6;
  const int bb = blockIdx.x >> 5;
  const int n0 = (blockIdx.x & 31) << 6;
  const int l15 = ln & 15, l4 = ln >> 4;
  const int dbase = wv * 32;

  short8 af[2][4];
#pragma unroll
  for (int dt = 0; dt < 2; ++dt)
#pragma unroll
    for (int ks = 0; ks < 4; ++ks) {
      short8 a;
#pragma unroll
      for (int j = 0; j < 8; ++j)
        a[j] = (short)f2bf_bits(W[(size_t)(ks * 32 + l4 * 8 + j) * DD + dbase + dt * 16 + l15]);
      af[dt][ks] = a;
    }

  f32x4 acc[2][4];
#pragma unroll
  for (int dt = 0; dt < 2; ++dt)
#pragma unroll
    for (int nt = 0; nt < 4; ++nt) acc[dt][nt] = (f32x4)0.0f;

  const float* xb = x + (size_t)bb * NN * DD;
  const float* dnb = dnorm + (size_t)bb * NN;
#pragma unroll
  for (int nt = 0; nt < 4; ++nt) {
    const int n = n0 + nt * 16 + l15;
    const float dn = dnb[n];
#pragma unroll
    for (int ks = 0; ks < 4; ++ks) {
      f32x4 p = *(const f32x4*)(xb + (size_t)n * DD + ks * 32 + l4 * 8);
      f32x4 q = *(const f32x4*)(xb + (size_t)n * DD + ks * 32 + l4 * 8 + 4);
      short8 bf = cvt8(p * dn, q * dn);
#pragma unroll
      for (int dt = 0; dt < 2; ++dt)
        acc[dt][nt] = __builtin_amdgcn_mfma_f32_16x16x32_bf16(af[dt][ks], bf, acc[dt][nt], 0, 0, 0);
    }
  }

  short* yb = yT + (size_t)bb * DD * NN;
#pragma unroll
  for (int dt = 0; dt < 2; ++dt)
#pragma unroll
    for (int nt = 0; nt < 4; ++nt)
#pragma unroll
      for (int rr = 0; rr < 4; ++rr) {
        int d = dbase + dt * 16 + l4 * 4 + rr;
        yb[(size_t)d * NN + n0 + nt * 16 + l15] = (short)f2bf_bits(acc[dt][nt][rr]);
      }
}

// ---------- K3: reuse-blocked GEMM ----------
// Fixed-cost isolation across r2..r15: GEMM fixed ~18 µs = LDS-read
// amplification (all 8 waves re-read the whole A tile: 8x). Here:
// BM=32, grid 512 -> 2 independent blocks/CU (16 waves/CU); 8 waves =
// 2 m-stripes x 4 d-quarters, 2 c-tiles per wave -> A-frag reused 2x,
// m-stripe read by only 4 waves: LDS reads 4 MB -> 2 MB per CU (~7 µs,
// hidden). Staging: r15's contiguous 1 KB-per-row gld16, ln^(row&7)
// 16B-unit swizzle (verified r15). BK=256 super-tiles, 2-buf LDS,
// 8 barriers total; B(S+1) fully prefetched into E/O register sets;
// vmcnt(16) end-of-iter retires staging only, leaves B in flight.
__launch_bounds__(512, 2)
__global__ void k_gemm5(const float* __restrict__ adj, const short* __restrict__ yT,
                        const float* __restrict__ dnorm, const float* __restrict__ bias,
                        float* __restrict__ out) {
  __shared__ char As[2][32768];  // 2 x 32 KB: [32 rows][1 KB]

  const int t = threadIdx.x;
  const int ln = t & 63;
  const int wv = t >> 6;
  const int l15 = ln & 15, l4 = ln >> 4;
  const int ms = wv >> 2;          // m-stripe 0..1 (16 rows)
  const int dq = wv & 3;           // d-quarter 0..3 (32 cols)
  // XCD-bijective swizzle: nwg=512, 64 per XCD; XCD x owns batch x
  const int orig = ((blockIdx.x & 7) << 6) | (blockIdx.x >> 3);
  const int bb = orig >> 6;
  const int m0 = (orig & 63) << 5;

  const char* ablk = (const char*)(adj + ((size_t)bb * NN + m0) * NN);
  const int oc0 = (dq << 5) + l15;          // c=0 column
  const int oc1 = oc0 + 16;                 // c=1 column
  const int kg8 = l4 << 3;
  const short* yb0 = yT + ((size_t)bb * DD + oc0) * NN + kg8;
  const short* yb1 = yT + ((size_t)bb * DD + oc1) * NN + kg8;

  f32x4 acc0 = (f32x4)0.f, acc1 = (f32x4)0.f;

  // stage super-tile S: wave stages rows wv*4..wv*4+4, each one contiguous
  // 1 KB wave read; source 16B-unit XOR ln^(row&7), LDS dest linear.
  auto stage = [&](int S, int buf) {
#pragma unroll
    for (int i = 0; i < 4; ++i) {
      const int row = (wv << 2) + i;
      const char* src = ablk + (size_t)row * (NN * 4) + (size_t)S * 1024 +
                        (((unsigned)(ln ^ (row & 7))) << 4);
      gld16(src, (char*)As + (buf << 15) + ((unsigned)row << 10));
    }
  };
  auto loadB = [&](int S, short8 B0[8], short8 B1[8]) {
#pragma unroll
    for (int kk = 0; kk < 8; ++kk) {
      B0[kk] = *(const short8*)(yb0 + S * 256 + kk * 32);
      B1[kk] = *(const short8*)(yb1 + S * 256 + kk * 32);
    }
  };
  auto compute = [&](int buf, short8 B0[8], short8 B1[8]) {
    const char* base = (const char*)As + (buf << 15);
    const unsigned row = (unsigned)((ms << 4) + l15);
    const unsigned s = row & 7u;
    const char* rbase = base + (row << 10);
#pragma unroll
    for (int kk = 0; kk < 8; ++kk) {
      const unsigned q0 = (unsigned)(kk * 8 + l4 * 2);
      f32x4 f0 = *(const f32x4*)(rbase + ((q0 ^ s) << 4));
      f32x4 f1 = *(const f32x4*)(rbase + (((q0 + 1) ^ s) << 4));
      short8 af = cvt8(f0, f1);
      acc0 = __builtin_amdgcn_mfma_f32_16x16x32_bf16(af, B0[kk], acc0, 0, 0, 0);
      acc1 = __builtin_amdgcn_mfma_f32_16x16x32_bf16(af, B1[kk], acc1, 0, 0, 0);
    }
  };

  short8 E0[8], E1[8], O0[8], O1[8];
  stage(0, 0);
  loadB(0, E0, E1);
  asm volatile("s_waitcnt vmcnt(0)\n\ts_barrier" ::: "memory");

#pragma unroll 1
  for (int S2 = 0; S2 < 8; S2 += 2) {
    // even super-tile
    if (S2 + 1 < 8) { stage(S2 + 1, 1); loadB(S2 + 1, O0, O1); }
    compute(0, E0, E1);
    if (S2 + 1 < 8) {
      asm volatile("s_waitcnt vmcnt(16)\n\ts_barrier" ::: "memory");
      // odd super-tile
      if (S2 + 2 < 8) { stage(S2 + 2, 0); loadB(S2 + 2, E0, E1); }
      compute(1, O0, O1);
      if (S2 + 2 < 8)
        asm volatile("s_waitcnt vmcnt(16)\n\ts_barrier" ::: "memory");
    }
  }

  // epilogue: out = dnorm_row * acc + bias
  const float bv0 = bias[oc0];
  const float bv1 = bias[oc1];
  const int rb = (ms << 4) + (l4 << 2);
  f32x4 dn4 = *(const f32x4*)(dnorm + (size_t)bb * NN + m0 + rb);
#pragma unroll
  for (int rr = 0; rr < 4; ++rr) {
    const size_t base = (size_t)(bb * NN + m0 + rb + rr) * DD;
    out[base + oc0] = acc0[rr] * dn4[rr] + bv0;
    out[base + oc1] = acc1[rr] * dn4[rr] + bv1;
  }
}

extern "C" void kernel_launch(void* const* d_in, const int* in_sizes, int n_in,
                              void* d_out, int out_size, void* d_ws, size_t ws_size,
                              hipStream_t stream) {
  (void)in_sizes; (void)n_in; (void)out_size; (void)ws_size;
  const float* x = (const float*)d_in[0];
  const float* adj = (const float*)d_in[1];
  const float* W = (const float*)d_in[2];
  const float* bias = (const float*)d_in[3];
  float* out = (float*)d_out;

  char* ws = (char*)d_ws;
  float* dnorm = (float*)ws;             // 64 KB
  short* yT = (short*)(ws + (1 << 16));  // 4 MB

  k_degree<<<4096, 256, 0, stream>>>(adj, dnorm);
  k_y<<<256, 256, 0, stream>>>(x, W, dnorm, yT);
  k_gemm5<<<512, 512, 0, stream>>>(adj, yT, dnorm, bias, out);
}

// Round 17
// 75.937 us; speedup vs baseline: 1.4150x; 1.4150x over previous
//
#include <hip/hip_runtime.h>
#include <hip/hip_bf16.h>

#define NN 2048
#define DD 128

typedef __attribute__((ext_vector_type(4))) float f32x4;
typedef __attribute__((ext_vector_type(16))) float f32x16;
typedef __attribute__((ext_vector_type(8))) short short8;

__device__ __forceinline__ unsigned short f2bf_bits(float f) {
  union { __hip_bfloat16 h; unsigned short s; } u;
  u.h = __float2bfloat16(f);
  return u.s;
}

__device__ __forceinline__ short8 cvt8(f32x4 a, f32x4 b) {
  short8 r;
  r[0] = (short)f2bf_bits(a[0]); r[1] = (short)f2bf_bits(a[1]);
  r[2] = (short)f2bf_bits(a[2]); r[3] = (short)f2bf_bits(a[3]);
  r[4] = (short)f2bf_bits(b[0]); r[5] = (short)f2bf_bits(b[1]);
  r[6] = (short)f2bf_bits(b[2]); r[7] = (short)f2bf_bits(b[3]);
  return r;
}

__device__ __forceinline__ void gld16(const void* src, void* lds) {
  __builtin_amdgcn_global_load_lds(
      (const __attribute__((address_space(1))) void*)src,
      (__attribute__((address_space(3))) void*)lds, 16, 0, 0);
}

// ---------- K1: dnorm = rsqrt(rowsum(adj)+1e-8) (proven, ~21 µs) ----------
__global__ void k_degree(const float* __restrict__ adj, float* __restrict__ dnorm) {
  const int wv = threadIdx.x >> 6;
  const int ln = threadIdx.x & 63;
  const int row = blockIdx.x * 4 + wv;
  const f32x4* rowp = (const f32x4*)(adj + (size_t)row * NN);
  float s = 0.0f;
#pragma unroll
  for (int i = 0; i < 8; ++i) {
    f32x4 v = rowp[i * 64 + ln];
    s += v[0] + v[1] + v[2] + v[3];
  }
#pragma unroll
  for (int off = 32; off >= 1; off >>= 1) s += __shfl_xor(s, off);
  if (ln == 0) dnorm[row] = rsqrtf(s + 1e-8f);
}

// ---------- K2: yT[b][d][n] = bf16(dnorm[n] * (x@W)[n][d]) (proven) ----------
__global__ void k_y(const float* __restrict__ x, const float* __restrict__ W,
                    const float* __restrict__ dnorm, short* __restrict__ yT) {
  const int ln = threadIdx.x & 63;
  const int wv = threadIdx.x >> 6;
  const int bb = blockIdx.x >> 5;
  const int n0 = (blockIdx.x & 31) << 6;
  const int l15 = ln & 15, l4 = ln >> 4;
  const int dbase = wv * 32;

  short8 af[2][4];
#pragma unroll
  for (int dt = 0; dt < 2; ++dt)
#pragma unroll
    for (int ks = 0; ks < 4; ++ks) {
      short8 a;
#pragma unroll
      for (int j = 0; j < 8; ++j)
        a[j] = (short)f2bf_bits(W[(size_t)(ks * 32 + l4 * 8 + j) * DD + dbase + dt * 16 + l15]);
      af[dt][ks] = a;
    }

  f32x4 acc[2][4];
#pragma unroll
  for (int dt = 0; dt < 2; ++dt)
#pragma unroll
    for (int nt = 0; nt < 4; ++nt) acc[dt][nt] = (f32x4)0.0f;

  const float* xb = x + (size_t)bb * NN * DD;
  const float* dnb = dnorm + (size_t)bb * NN;
#pragma unroll
  for (int nt = 0; nt < 4; ++nt) {
    const int n = n0 + nt * 16 + l15;
    const float dn = dnb[n];
#pragma unroll
    for (int ks = 0; ks < 4; ++ks) {
      f32x4 p = *(const f32x4*)(xb + (size_t)n * DD + ks * 32 + l4 * 8);
      f32x4 q = *(const f32x4*)(xb + (size_t)n * DD + ks * 32 + l4 * 8 + 4);
      short8 bf = cvt8(p * dn, q * dn);
#pragma unroll
      for (int dt = 0; dt < 2; ++dt)
        acc[dt][nt] = __builtin_amdgcn_mfma_f32_16x16x32_bf16(af[dt][ks], bf, acc[dt][nt], 0, 0, 0);
    }
  }

  short* yb = yT + (size_t)bb * DD * NN;
#pragma unroll
  for (int dt = 0; dt < 2; ++dt)
#pragma unroll
    for (int nt = 0; nt < 4; ++nt)
#pragma unroll
      for (int rr = 0; rr < 4; ++rr) {
        int d = dbase + dt * 16 + l4 * 4 + rr;
        yb[(size_t)d * NN + n0 + nt * 16 + l15] = (short)f2bf_bits(acc[dt][nt][rr]);
      }
}

// ---------- K3: out = dnorm_row * (adj @ y) + b — 32x32x16 MFMA ----------
// r16's counters isolated the GEMM bottleneck: LDS-read throughput
// (128 ds_read_b128/K-tile/CU ≈ 20.5 µs serialized; not HBM, not barriers).
// Fix: 32x32x16 MFMA = 2x FLOPs per operand byte + 2 m-stripes x 4
// col-groups (A-frag read by 4 waves not 8) -> 64 b128/K-tile (~10 µs).
// Staging/cadence/swizzle = r12 VERBATIM. B: 2 slots x 4 short8 (32 VGPR,
// no spill — r16's bug); refill loads go directly into the slot right
// after its MFMA consumed it (no reg-copy -> no forced vmcnt(0)).
// vmcnt(16) re-counted: 6 VMEM/iter, stage(T+1) has 16 younger ops.
// C-layout 32x32 (HW-verified m74/m101): col=lane&31,
// row=(reg&3)+8(reg>>2)+4(lane>>5). A/B: row/col=lane&31, k=(lane>>5)*8+j.
__launch_bounds__(512, 1)
__global__ void k_gemm6(const float* __restrict__ adj, const short* __restrict__ yT,
                        const float* __restrict__ dnorm, const float* __restrict__ bias,
                        float* __restrict__ out) {
  __shared__ float As[4][4096];  // 4 x 16 KB: [64 rows][64 k] f32, 256 B rows

  const int t = threadIdx.x;
  const int ln = t & 63;
  const int wv = t >> 6;
  const int l31 = ln & 31, lhi = ln >> 5;
  const int ms = wv >> 2;          // m-stripe 0..1 (32 rows)
  const int dq = wv & 3;           // col-group 0..3 (32 cols)
  const int orig = ((blockIdx.x & 7) << 5) | (blockIdx.x >> 3);  // XCD-bijective
  const int bb = orig >> 5;
  const int m0 = (orig & 31) << 6;

  const char* ablk = (const char*)(adj + ((size_t)bb * NN + m0) * NN);
  const int col = (dq << 5) + l31;                 // this lane's output col
  const short* ybase = yT + ((size_t)bb * DD + col) * NN + (lhi << 3);

  f32x16 acc = (f32x16)0.0f;

  auto stage = [&](int tile, int buf) {            // r12-verbatim
#pragma unroll
    for (int j = 0; j < 2; ++j) {
      unsigned L = ((unsigned)j << 13) + ((unsigned)t << 4);
      unsigned row = L >> 8;
      unsigned off = L & 255u;
      unsigned soff = off ^ ((row & 7u) << 4);
      const char* src = ablk + (size_t)row * (NN * 4) + (size_t)tile * 256 + soff;
      gld16(src, (char*)As + buf * 16384 + L);
    }
  };
  // B[ksp] = yT[col][tile*64 + ksp*16 + lhi*8 .. +8]  (16B contiguous)
  auto loadB = [&](int tile, short8 B[4]) {
#pragma unroll
    for (int ksp = 0; ksp < 4; ++ksp)
      B[ksp] = *(const short8*)(ybase + (tile << 6) + ksp * 16);
  };
  auto compute = [&](int buf, short8 B[4]) {
    const char* base = (const char*)As + buf * 16384;
    const unsigned row = (unsigned)((ms << 5) + l31);       // 0..63
    const unsigned sw = (row & 7u) << 4;
    const char* rbase = base + (row << 8);
    const unsigned kh = (unsigned)lhi << 5;                 // 0 or 32 B
#pragma unroll
    for (int ksp = 0; ksp < 4; ++ksp) {
      unsigned c = (unsigned)(ksp * 64) + kh;
      f32x4 f0 = *(const f32x4*)(rbase + (c ^ sw));
      f32x4 f1 = *(const f32x4*)(rbase + ((c + 16) ^ sw));
      acc = __builtin_amdgcn_mfma_f32_32x32x16_bf16(cvt8(f0, f1), B[ksp], acc, 0, 0, 0);
    }
  };

  short8 E[4], O[4];
  stage(0, 0); stage(1, 1); stage(2, 2);
  loadB(0, E); loadB(1, O);
  asm volatile("s_waitcnt vmcnt(0)\n\ts_barrier" ::: "memory");

  // GITER(T): stage(T+3); compute(T) consuming BSLOT; refill BSLOT <- B(T+2)
  // (issued after the MFMAs consumed it — no WAR stall); vmcnt(16)+barrier.
#define GITER(T, BSLOT)                                                 \
  {                                                                     \
    stage(((T) + 3) & 31, ((T) + 3) & 3);                               \
    compute((T) & 3, BSLOT);                                            \
    loadB(((T) + 2) & 31, BSLOT);                                       \
    asm volatile("s_waitcnt vmcnt(16)\n\ts_barrier" ::: "memory");      \
  }

#pragma unroll 1
  for (int t2 = 0; t2 < 32; t2 += 2) {
    GITER(t2 + 0, E);
    GITER(t2 + 1, O);
  }
#undef GITER

  // epilogue: out = dnorm_row * acc + bias (C-layout m74/m101)
  const float bv = bias[col];
  const int rowbase = m0 + (ms << 5) + (lhi << 2);
#pragma unroll
  for (int q = 0; q < 4; ++q) {
    f32x4 dn4 = *(const f32x4*)(dnorm + (size_t)bb * NN + rowbase + 8 * q);
#pragma unroll
    for (int j = 0; j < 4; ++j) {
      const int row = rowbase + 8 * q + j;
      out[((size_t)bb * NN + row) * DD + col] = acc[q * 4 + j] * dn4[j] + bv;
    }
  }
}

extern "C" void kernel_launch(void* const* d_in, const int* in_sizes, int n_in,
                              void* d_out, int out_size, void* d_ws, size_t ws_size,
                              hipStream_t stream) {
  (void)in_sizes; (void)n_in; (void)out_size; (void)ws_size;
  const float* x = (const float*)d_in[0];
  const float* adj = (const float*)d_in[1];
  const float* W = (const float*)d_in[2];
  const float* bias = (const float*)d_in[3];
  float* out = (float*)d_out;

  char* ws = (char*)d_ws;
  float* dnorm = (float*)ws;             // 64 KB
  short* yT = (short*)(ws + (1 << 16));  // 4 MB

  k_degree<<<4096, 256, 0, stream>>>(adj, dnorm);
  k_y<<<256, 256, 0, stream>>>(x, W, dnorm, yT);
  k_gemm6<<<256, 512, 0, stream>>>(adj, yT, dnorm, bias, out);
}